// Round 7
// baseline (136.859 us; speedup 1.0000x reference)
//
#include <hip/hip_runtime.h>
#include <math.h>

// ---------------------------------------------------------------------------
// DCMHSA fused pipeline, MI355X (gfx950)
// B=8, DIM=384, H=W=64 (S=4096), HEADS=8, D=48, D2=24, DU=32, OC=3*DIM=1152
// R7: k1 -> 576 persistent-ish blocks, 4 s-tiles/block, one continuous 48-step
//     counted-vmcnt prefetch pipeline (amortizes prologue/epilogue).
//     cmraw/c2raw/msp demoted to bf16 (saves ~42 MB HBM).
// ---------------------------------------------------------------------------

#define S4096 4096
#define C384  384
#define OC    1152

typedef unsigned short bfraw;   // bf16 bit pattern
typedef unsigned int   u32;
typedef __attribute__((ext_vector_type(8))) short bf16x8;   // 8 bf16 (4 VGPRs)
typedef __attribute__((ext_vector_type(4))) float f32x4;    // MFMA accumulator

typedef __attribute__((address_space(3))) unsigned int lds_u32;
typedef const __attribute__((address_space(1))) unsigned int glb_u32;
__device__ __forceinline__ void gll16(const void* g, void* l) {
    __builtin_amdgcn_global_load_lds((glb_u32*)g, (lds_u32*)l, 16, 0, 0);
}

__device__ __forceinline__ bfraw f2bf(float f) {
    union { float f; u32 u; } c; c.f = f;
    u32 r = c.u + 0x7FFFu + ((c.u >> 16) & 1u);   // RNE
    return (bfraw)(r >> 16);
}
__device__ __forceinline__ float bf2f(bfraw u) {
    union { u32 u; float f; } c; c.u = ((u32)u) << 16;
    return c.f;
}
__device__ __forceinline__ void unpack8(uint4 v, float* f) {
    f[0] = bf2f((bfraw)(v.x & 0xffff)); f[1] = bf2f((bfraw)(v.x >> 16));
    f[2] = bf2f((bfraw)(v.y & 0xffff)); f[3] = bf2f((bfraw)(v.y >> 16));
    f[4] = bf2f((bfraw)(v.z & 0xffff)); f[5] = bf2f((bfraw)(v.z >> 16));
    f[6] = bf2f((bfraw)(v.w & 0xffff)); f[7] = bf2f((bfraw)(v.w >> 16));
}
__device__ __forceinline__ uint4 pack8(const float* f) {
    union { bfraw us[8]; uint4 q; } p;
    #pragma unroll
    for (int i = 0; i < 8; i++) p.us[i] = f2bf(f[i]);
    return p.q;
}

// block=256 (4 waves) reduction; s4 is 4-float shared scratch
__device__ __forceinline__ float blk_red(float v, float* s4, bool ismax) {
    #pragma unroll
    for (int off = 32; off; off >>= 1) {
        float o = __shfl_down(v, off, 64);
        v = ismax ? fmaxf(v, o) : (v + o);
    }
    __syncthreads();                       // protect prior contents of s4
    if ((threadIdx.x & 63) == 0) s4[threadIdx.x >> 6] = v;
    __syncthreads();
    return ismax ? fmaxf(fmaxf(s4[0], s4[1]), fmaxf(s4[2], s4[3]))
                 : ((s4[0] + s4[1]) + (s4[2] + s4[3]));
}

// ---------------------------------------------------------------------------
// kA: blocks 0..215: w_qkv [1152][384] f32 -> wF fragment layout bf16.
//     block 216: data-independent weff prep.
// ---------------------------------------------------------------------------
__global__ __launch_bounds__(256) void kA_prep(
    const float* __restrict__ w_qkv, bfraw* __restrict__ wF,
    const float* __restrict__ w_attn_l, const float* __restrict__ w_v_l,
    float* __restrict__ weff) {
    if (blockIdx.x == 216) {
        __shared__ float avg[24];
        const int tid = threadIdx.x;
        if (tid < 24) {
            float a = 0.f;
            for (int d = 0; d < 48; d++) a += w_attn_l[tid * 48 + d];
            avg[tid] = a * (1.f / 4096.f);
        }
        __syncthreads();
        if (tid == 0) {
            float M = -3.402823466e+38f;
            for (int o = 0; o < 24; o++) M = fmaxf(M, avg[o]);
            float S = 0.f;
            for (int o = 0; o < 24; o++) { avg[o] = __expf(avg[o] - M); S += avg[o]; }
            float inv = 1.f / S;
            for (int o = 0; o < 24; o++) avg[o] *= inv;
        }
        __syncthreads();
        if (tid < 48) {
            float a = 0.f;
            for (int o = 0; o < 24; o++) a += avg[o] * w_v_l[o * 48 + tid];
            weff[tid] = a;
        }
        return;
    }
    const int id = blockIdx.x * 256 + threadIdx.x;   // < 55296
    const int ob = id / 768, rem = id % 768;
    const int c = rem / 48, kb = rem % 48;
    const float* src = w_qkv + (size_t)(ob * 16 + c) * C384 + kb * 8;
    float f[8];
    *(float4*)f       = *(const float4*)src;
    *(float4*)(f + 4) = *(const float4*)(src + 4);
    *(uint4*)&wF[((size_t)(ob * 48 + kb) * 16 + c) * 8] = pack8(f);
}

// ---------------------------------------------------------------------------
// kB: transpose+convert x[b][c][s] f32 -> xF[b][s/16][k/8][16][8] bf16.
// ---------------------------------------------------------------------------
__global__ __launch_bounds__(256) void kB_tr(
    const float* __restrict__ x, bfraw* __restrict__ xF, int b0) {
    const int cb = blockIdx.x, sb = blockIdx.y, bl = blockIdx.z;
    const int c0 = cb * 16, s0 = sb * 256;
    const int tid = threadIdx.x;
    __shared__ alignas(16) bfraw lt[16][264];   // pad 8 u16 (16 B)
    {
        const int r = tid >> 4, seg = tid & 15;
        const float* src = x + ((size_t)(b0 + bl) * C384 + c0 + r) * S4096 + s0 + seg * 16;
        float f[16];
        #pragma unroll
        for (int i = 0; i < 4; i++) *(float4*)(f + i * 4) = *(const float4*)(src + i * 4);
        *(uint4*)&lt[r][seg * 16]     = pack8(f);
        *(uint4*)&lt[r][seg * 16 + 8] = pack8(f + 8);
    }
    __syncthreads();
    const int sbl = tid >> 4, c = tid & 15;
    bfraw* xFb = xF + (size_t)bl * S4096 * C384;
    #pragma unroll
    for (int kbl = 0; kbl < 2; kbl++) {
        union { bfraw us[8]; uint4 q; } p;
        #pragma unroll
        for (int j = 0; j < 8; j++) p.us[j] = lt[kbl * 8 + j][sbl * 16 + c];
        const size_t idx = (((size_t)((s0 >> 4) + sbl) * 48) + (c0 >> 3) + kbl) * 128 + c * 8;
        *(uint4*)&xFb[idx] = p.q;
    }
}

// ---------------------------------------------------------------------------
// k1: pre[b,o,s] = sum_c w[o,c] x[b,c,s]  -- 128x128 tile, BK=32, 4 waves.
// 576 blocks (fully co-resident); each handles 4 s-tiles via one continuous
// 48-step pipeline: 3 LDS buffers, 2-deep prefetch, counted vmcnt(4).
// grid (8 sG, 9 oT, nb)
// ---------------------------------------------------------------------------
__global__ __launch_bounds__(256) void k1_gemm(
    const bfraw* __restrict__ wF, const bfraw* __restrict__ xF,
    bfraw* __restrict__ pre, int b0) {
    __shared__ alignas(16) bfraw smem[24576];   // 3 x 16 KB
    const int tid = threadIdx.x;
    const int wave = tid >> 6, lane = tid & 63;
    const int sG = blockIdx.x, oT = blockIdx.y, bl = blockIdx.z;
    const bfraw* xFb = xF + (size_t)bl * S4096 * C384;

    const int c0_ = tid, c1_ = tid + 256;
    const int rb0 = c0_ >> 6, oc0 = (c0_ >> 4) & 3, rw0 = c0_ & 15;
    const int rb1 = c1_ >> 6, oc1 = (c1_ >> 4) & 3, rw1 = c1_ & 15;

    // per-thread staging base pointers (ks=0, st=0)
    const bfraw* pA0 = wF + ((size_t)((oT * 8 + rb0) * 48 + oc0) * 16 + rw0) * 8;
    const bfraw* pA1 = wF + ((size_t)((oT * 8 + rb1) * 48 + oc1) * 16 + rw1) * 8;
    const bfraw* pB0 = xFb + ((size_t)((sG * 32 + rb0) * 48 + oc0) * 16 + rw0) * 8;
    const bfraw* pB1 = xFb + ((size_t)((sG * 32 + rb1) * 48 + oc1) * 16 + rw1) * 8;

    auto stage = [&](bfraw* dst, int ks, int st) {
        const int ko = ks * 512;               // 4 oct-units * 128
        const int so = st * 49152 + ko;        // 8 rb-units * 48 * 128
        gll16(pA0 + ko, dst + (size_t)c0_ * 8);
        gll16(pA1 + ko, dst + (size_t)c1_ * 8);
        gll16(pB0 + so, dst + 4096 + (size_t)c0_ * 8);
        gll16(pB1 + so, dst + 4096 + (size_t)c1_ * 8);
    };

    f32x4 acc[4][4];
    #pragma unroll
    for (int m = 0; m < 4; m++)
        #pragma unroll
        for (int n = 0; n < 4; n++) acc[m][n] = (f32x4){0, 0, 0, 0};

    const int wr = (wave >> 1) * 4;   // A frag base (16-row units)
    const int wc = (wave & 1) * 4;    // B frag base (16-col units)
    const int orow0 = oT * 128 + (wave >> 1) * 64 + (lane >> 4) * 4;
    bfraw* op = pre + (size_t)bl * OC * S4096;

    stage(smem,        0, 0);
    stage(smem + 8192, 1, 0);
    int ks_p = 2, st_p = 0, bp = 2;   // prefetch state (2 steps ahead)
    int ks_c = 0, st_c = 0, bi = 0;   // compute state

    for (int i = 0; i < 48; ++i) {
        if (i < 47) asm volatile("s_waitcnt vmcnt(4)" ::: "memory");
        else        asm volatile("s_waitcnt vmcnt(0)" ::: "memory");
        __builtin_amdgcn_s_barrier();
        const bfraw* cb = smem + bi * 8192;
        bf16x8 af[4], bq[4];
        #pragma unroll
        for (int m = 0; m < 4; m++)
            af[m] = *(const bf16x8*)&cb[((wr + m) * 64 + lane) * 8];
        #pragma unroll
        for (int n = 0; n < 4; n++)
            bq[n] = *(const bf16x8*)&cb[4096 + ((wc + n) * 64 + lane) * 8];
        if (i < 46) {
            stage(smem + bp * 8192, ks_p, st_p);
            if (++ks_p == 12) { ks_p = 0; ++st_p; }
            bp = (bp == 2) ? 0 : bp + 1;
        }
        __builtin_amdgcn_s_setprio(1);
        #pragma unroll
        for (int m = 0; m < 4; m++)
            #pragma unroll
            for (int n = 0; n < 4; n++)
                acc[m][n] = __builtin_amdgcn_mfma_f32_16x16x32_bf16(af[m], bq[n], acc[m][n], 0, 0, 0);
        __builtin_amdgcn_s_setprio(0);
        if (++ks_c == 12) {
            // epilogue for finished s-tile st_c
            const int scol0 = (sG * 4 + st_c) * 128 + (wave & 1) * 64 + (lane & 15);
            #pragma unroll
            for (int m = 0; m < 4; m++)
                #pragma unroll
                for (int n = 0; n < 4; n++)
                    #pragma unroll
                    for (int r = 0; r < 4; r++)
                        op[(size_t)(orow0 + m * 16 + r) * S4096 + scol0 + n * 16] = f2bf(acc[m][n][r]);
            #pragma unroll
            for (int m = 0; m < 4; m++)
                #pragma unroll
                for (int n = 0; n < 4; n++) acc[m][n] = (f32x4){0, 0, 0, 0};
            ks_c = 0; ++st_c;
        }
        bi = (bi == 2) ? 0 : bi + 1;
    }
}

// ---------------------------------------------------------------------------
// k2f: fused depthwise 3x3 + norms + softmax stats + attn write.
// ---------------------------------------------------------------------------
__device__ __forceinline__ void stencil8(const bfraw* plane, const float* w9,
                                         int ypad, int k7, int x0, float* acc) {
    #pragma unroll
    for (int j = 0; j < 8; j++) acc[j] = 0.f;
    #pragma unroll
    for (int dy = 0; dy < 3; dy++) {
        uint4 rv = *(const uint4*)&plane[(ypad + dy) * 64 + x0];
        float r[8]; unpack8(rv, r);
        float lft = __shfl_up(r[7], 1);
        float rgt = __shfl_down(r[0], 1);
        if (k7 == 0) lft = 0.f;
        if (k7 == 7) rgt = 0.f;
        const float w0 = w9[dy*3], w1 = w9[dy*3+1], w2 = w9[dy*3+2];
        acc[0] += w0*lft + w1*r[0] + w2*r[1];
        #pragma unroll
        for (int j = 1; j < 7; j++) acc[j] += w0*r[j-1] + w1*r[j] + w2*r[j+1];
        acc[7] += w0*r[6] + w1*r[7] + w2*rgt;
    }
}

__global__ __launch_bounds__(256) void k2f(
    const bfraw* __restrict__ pre, const float* __restrict__ w_dw,
    const float* __restrict__ temperature,
    bfraw* __restrict__ av, int b0) {
    const int idx = blockIdx.x;            // h*48+d
    const int bl  = blockIdx.y;
    const int h   = idx / 48;
    const int tid = threadIdx.x;
    __shared__ alignas(16) bfraw pl[3][66 * 64];   // rows -1..64 zero-padded
    __shared__ float s4[4];

    const size_t pbase = (size_t)bl * OC * S4096;
    #pragma unroll
    for (int p = 0; p < 3; p++) {
        const bfraw* src = pre + pbase + (size_t)(idx + p * C384) * S4096;
        uint4 a = *(const uint4*)&src[tid * 16];
        uint4 b = *(const uint4*)&src[tid * 16 + 8];
        int y = tid >> 2, xq = (tid & 3) * 16;
        *(uint4*)&pl[p][(y + 1) * 64 + xq]     = a;
        *(uint4*)&pl[p][(y + 1) * 64 + xq + 8] = b;
    }
    if (tid < 64) {
        #pragma unroll
        for (int p = 0; p < 3; p++) { pl[p][tid] = 0; pl[p][65 * 64 + tid] = 0; }
    }
    float wq[9], wk[9], wv[9];
    #pragma unroll
    for (int i = 0; i < 9; i++) {
        wq[i] = w_dw[idx * 9 + i];
        wk[i] = w_dw[(idx + C384) * 9 + i];
        wv[i] = w_dw[(idx + 768) * 9 + i];
    }
    __syncthreads();

    const int sid0 = tid,        y0 = sid0 >> 3, k70 = sid0 & 7, x00 = k70 * 8;
    const int sid1 = tid + 256,  y1 = sid1 >> 3, k71 = sid1 & 7, x01 = k71 * 8;
    float qo[16], ko[16], vo[16];
    stencil8(pl[0], wq, y0, k70, x00, qo);
    stencil8(pl[0], wq, y1, k71, x01, qo + 8);
    stencil8(pl[1], wk, y0, k70, x00, ko);
    stencil8(pl[1], wk, y1, k71, x01, ko + 8);
    stencil8(pl[2], wv, y0, k70, x00, vo);
    stencil8(pl[2], wv, y1, k71, x01, vo + 8);

    float sq = 0.f, sk = 0.f;
    #pragma unroll
    for (int i = 0; i < 16; i++) { sq += qo[i] * qo[i]; sk += ko[i] * ko[i]; }
    float Sq = blk_red(sq, s4, false);
    float Sk = blk_red(sk, s4, false);
    float scale = temperature[h] /
        (fmaxf(sqrtf(Sq), 1e-12f) * fmaxf(sqrtf(Sk), 1e-12f));
    float lm = -3.402823466e+38f;
    #pragma unroll
    for (int i = 0; i < 16; i++) { qo[i] = qo[i] * ko[i] * scale; lm = fmaxf(lm, qo[i]); }
    float M = blk_red(lm, s4, true);
    float ls = 0.f;
    #pragma unroll
    for (int i = 0; i < 16; i++) { qo[i] = __expf(qo[i] - M); ls += qo[i]; }
    float Z = blk_red(ls, s4, false);
    float invZ = 1.f / Z;
    #pragma unroll
    for (int i = 0; i < 16; i++) qo[i] *= invZ;

    bfraw* adst = av + ((size_t)bl * 768 + idx) * S4096;
    bfraw* vdst = av + ((size_t)bl * 768 + 384 + idx) * S4096;
    *(uint4*)&adst[y0 * 64 + x00] = pack8(qo);
    *(uint4*)&adst[y1 * 64 + x01] = pack8(qo + 8);
    *(uint4*)&vdst[y0 * 64 + x00] = pack8(vo);
    *(uint4*)&vdst[y1 * 64 + x01] = pack8(vo + 8);
}

// ---------------------------------------------------------------------------
// k4a: partial sums over d, s-tiled.  grid (8, nb, 4).  bf16 outputs.
// ---------------------------------------------------------------------------
__global__ __launch_bounds__(256) void k4a(
    const bfraw* __restrict__ av, const float* __restrict__ w_attn_r,
    const float* __restrict__ weff,
    bfraw* __restrict__ cmraw, bfraw* __restrict__ c2raw, int b0) {
    const int h = blockIdx.x, bl = blockIdx.y, st = blockIdx.z;
    const int b = b0 + bl;
    const int tid = threadIdx.x;
    __shared__ float swr[48], swf[48];
    if (tid < 48) { swr[tid] = w_attn_r[tid]; swf[tid] = weff[tid]; }
    __syncthreads();
    const int s_off = st * 1024 + tid * 4;
    const bfraw* abase = av + ((size_t)bl * 768 + h * 48) * S4096 + s_off;
    const bfraw* vbase = abase + (size_t)384 * S4096;
    float cmr[4] = {0,0,0,0}, c2[4] = {0,0,0,0};
    for (int d = 0; d < 48; d++) {
        uint2 ua = *(const uint2*)(abase + (size_t)d * S4096);
        uint2 uv = *(const uint2*)(vbase + (size_t)d * S4096);
        const float wr = swr[d], wf = swf[d];
        cmr[0] += bf2f((bfraw)(ua.x & 0xffff)) * wr;
        cmr[1] += bf2f((bfraw)(ua.x >> 16))    * wr;
        cmr[2] += bf2f((bfraw)(ua.y & 0xffff)) * wr;
        cmr[3] += bf2f((bfraw)(ua.y >> 16))    * wr;
        c2[0]  += bf2f((bfraw)(uv.x & 0xffff)) * wf;
        c2[1]  += bf2f((bfraw)(uv.x >> 16))    * wf;
        c2[2]  += bf2f((bfraw)(uv.y & 0xffff)) * wf;
        c2[3]  += bf2f((bfraw)(uv.y >> 16))    * wf;
    }
    const size_t o = ((size_t)(b * 8 + h)) * S4096 + s_off;
    union { bfraw us[4]; uint2 q; } pa, pb;
    #pragma unroll
    for (int j = 0; j < 4; j++) { pa.us[j] = f2bf(cmr[j]); pb.us[j] = f2bf(c2[j]); }
    *(uint2*)(cmraw + o) = pa.q;
    *(uint2*)(c2raw + o) = pb.q;
}

// ---------------------------------------------------------------------------
// k4b: softmax_s(cmraw) -> cmb (bf16);  sigmoid(c2raw) -> msp (bf16).
// ---------------------------------------------------------------------------
__global__ __launch_bounds__(256) void k4b(
    const bfraw* __restrict__ cmraw, const bfraw* __restrict__ c2raw,
    bfraw* __restrict__ cmb, bfraw* __restrict__ msp, int b0) {
    const int h = blockIdx.x, bl = blockIdx.y, b = b0 + bl;
    const int tid = threadIdx.x;
    __shared__ float s4[4];
    const size_t base = ((size_t)(b * 8 + h)) * S4096 + tid * 16;
    float v[16];
    { uint4 a = *(const uint4*)(cmraw + base), c = *(const uint4*)(cmraw + base + 8);
      unpack8(a, v); unpack8(c, v + 8); }
    float lm = -3.402823466e+38f;
    #pragma unroll
    for (int i = 0; i < 16; i++) lm = fmaxf(lm, v[i]);
    float M = blk_red(lm, s4, true);
    float ls = 0.f;
    #pragma unroll
    for (int i = 0; i < 16; i++) { v[i] = __expf(v[i] - M); ls += v[i]; }
    float Z = blk_red(ls, s4, false);
    float inv = 1.f / Z;
    #pragma unroll
    for (int i = 0; i < 16; i++) v[i] *= inv;
    *(uint4*)(cmb + base)     = pack8(v);
    *(uint4*)(cmb + base + 8) = pack8(v + 8);
    float sg[16];
    { uint4 a = *(const uint4*)(c2raw + base), c = *(const uint4*)(c2raw + base + 8);
      unpack8(a, sg); unpack8(c, sg + 8); }
    #pragma unroll
    for (int i = 0; i < 16; i++) sg[i] = 1.f / (1.f + __expf(-sg[i]));
    *(uint4*)(msp + base)     = pack8(sg);
    *(uint4*)(msp + base + 8) = pack8(sg + 8);
}

// ---------------------------------------------------------------------------
// k5: vc[b,h,d] = sum_s cmb[b,h,s]*v[b,h,d,s].   grid (384, nb)
// ---------------------------------------------------------------------------
__global__ __launch_bounds__(256) void k5_vc(
    const bfraw* __restrict__ av, const bfraw* __restrict__ cmb,
    float* __restrict__ vc, int b0) {
    const int idx = blockIdx.x;            // h*48+d
    const int bl = blockIdx.y, b = b0 + bl;
    const int h = idx / 48;
    const int tid = threadIdx.x;
    const bfraw* vr = av + ((size_t)bl * 768 + 384 + idx) * S4096 + tid * 16;
    const bfraw* cr = cmb + ((size_t)(b * 8 + h)) * S4096 + tid * 16;
    float vv[16], cc[16];
    { uint4 a = *(const uint4*)vr, c = *(const uint4*)(vr + 8); unpack8(a, vv); unpack8(c, vv + 8); }
    { uint4 a = *(const uint4*)cr, c = *(const uint4*)(cr + 8); unpack8(a, cc); unpack8(c, cc + 8); }
    float a = 0.f;
    #pragma unroll
    for (int i = 0; i < 16; i++) a += vv[i] * cc[i];
    __shared__ float s4[4];
    float S = blk_red(a, s4, false);
    if (tid == 0) vc[b * C384 + idx] = S;
}

// ---------------------------------------------------------------------------
// k6: channel gate: ctx -> up1 -> LayerNorm(32x8) -> relu -> up2 -> sigmoid.
// ---------------------------------------------------------------------------
__global__ __launch_bounds__(256) void k6_gate(
    const float* __restrict__ vc, const float* __restrict__ w_v_r,
    const float* __restrict__ w_up1, const float* __restrict__ b_up1,
    const float* __restrict__ ln_w, const float* __restrict__ ln_b,
    const float* __restrict__ w_up2, const float* __restrict__ b_up2,
    float* __restrict__ mch, int b0) {
    const int b = b0 + blockIdx.x;
    const int tid = threadIdx.x;
    __shared__ float s_vc[384], s_ctx[192], s_u[256], s4[4];
    for (int i = tid; i < 384; i += 256) s_vc[i] = vc[b * C384 + i];
    __syncthreads();
    if (tid < 192) {
        int hh = tid / 24, o = tid % 24;
        float a = 0.f;
        for (int d = 0; d < 48; d++) a += w_v_r[o * 48 + d] * s_vc[hh * 48 + d];
        s_ctx[hh * 24 + o] = a;
    }
    __syncthreads();
    float uval;
    {
        int o = tid >> 3, hh = tid & 7;
        float a = b_up1[o];
        for (int c = 0; c < 24; c++) a += w_up1[o * 24 + c] * s_ctx[hh * 24 + c];
        uval = a;
    }
    float mu  = blk_red(uval, s4, false) * (1.f / 256.f);
    float dv  = uval - mu;
    float var = blk_red(dv * dv, s4, false) * (1.f / 256.f);
    float un  = dv * rsqrtf(var + 1e-5f) * ln_w[tid] + ln_b[tid];
    s_u[tid] = fmaxf(un, 0.f);
    __syncthreads();
    for (int t = tid; t < 384; t += 256) {
        int o2 = t >> 3, hh = t & 7;
        float a = b_up2[o2];
        for (int o = 0; o < 32; o++) a += w_up2[o2 * 32 + o] * s_u[o * 8 + hh];
        mch[b * C384 + t] = 1.f / (1.f + __expf(-a));
    }
}

// ---------------------------------------------------------------------------
// k7: out[b,c,s] = x[b,c,s] * ( mask_ch[b,c] + sum_h w_proj[c,h]*msp[b,h,s] )
// grid (16 s-tiles of 256, 8 c-groups of 48, nb).  msp (bf16) -> LDS f32.
// ---------------------------------------------------------------------------
__global__ __launch_bounds__(256) void k7_out(
    const float* __restrict__ x, const float* __restrict__ w_proj,
    const float* __restrict__ mch, const bfraw* __restrict__ msp,
    float* __restrict__ out, int b0) {
    const int st = blockIdx.x, cg = blockIdx.y, bl = blockIdx.z;
    const int b = b0 + bl;
    const int tid = threadIdx.x;
    const int s0 = st * 256, c0 = cg * 48;
    __shared__ float s_msp[8][256];
    __shared__ float s_mch[48];
    __shared__ float s_wp[48][8];
    for (int i = tid; i < 2048; i += 256) {
        int hh = i >> 8, ss = i & 255;
        s_msp[hh][ss] = bf2f(msp[((size_t)(b * 8 + hh)) * S4096 + s0 + ss]);
    }
    if (tid < 48) s_mch[tid] = mch[b * C384 + c0 + tid];
    for (int i = tid; i < 384; i += 256)
        s_wp[i >> 3][i & 7] = w_proj[(size_t)(c0 + (i >> 3)) * 8 + (i & 7)];
    __syncthreads();

    const int cl = tid >> 6;           // 0..3 (wave-uniform)
    const int s4i = (tid & 63) * 4;    // float4 slot in s-tile
    float4 m[8];
    #pragma unroll
    for (int hh = 0; hh < 8; hh++) m[hh] = *(const float4*)&s_msp[hh][s4i];

    #pragma unroll 4
    for (int j = 0; j < 12; j++) {
        const int cloc = j * 4 + cl;
        const int c = c0 + cloc;
        const float base = s_mch[cloc];
        float4 a = {base, base, base, base};
        #pragma unroll
        for (int hh = 0; hh < 8; hh++) {
            const float wp = s_wp[cloc][hh];
            a.x += wp * m[hh].x; a.y += wp * m[hh].y;
            a.z += wp * m[hh].z; a.w += wp * m[hh].w;
        }
        const size_t o = ((size_t)b * C384 + c) * S4096 + s0 + s4i;
        float4 xv = *(const float4*)(x + o);
        a.x *= xv.x; a.y *= xv.y; a.z *= xv.z; a.w *= xv.w;
        *(float4*)(out + o) = a;
    }
}

// ---------------------------------------------------------------------------
extern "C" void kernel_launch(void* const* d_in, const int* in_sizes, int n_in,
                              void* d_out, int out_size, void* d_ws, size_t ws_size,
                              hipStream_t stream) {
    const float* x        = (const float*)d_in[0];
    const float* temp     = (const float*)d_in[1];
    const float* w_qkv    = (const float*)d_in[2];
    const float* w_dw     = (const float*)d_in[3];
    const float* w_proj   = (const float*)d_in[4];
    const float* w_attn_r = (const float*)d_in[5];
    const float* w_v_r    = (const float*)d_in[6];
    const float* w_up1    = (const float*)d_in[7];
    const float* b_up1    = (const float*)d_in[8];
    const float* ln_w     = (const float*)d_in[9];
    const float* ln_b     = (const float*)d_in[10];
    const float* w_up2    = (const float*)d_in[11];
    const float* b_up2    = (const float*)d_in[12];
    const float* w_attn_l = (const float*)d_in[13];
    const float* w_v_l    = (const float*)d_in[14];
    float* out = (float*)d_out;
    char* ws = (char*)d_ws;

    size_t off = 0;
    auto alloc = [&](size_t bytes) {
        size_t o = off; off = (off + bytes + 255) & ~(size_t)255; return o;
    };
    bfraw* cmraw = (bfraw*)(ws + alloc((size_t)64 * S4096 * 2));
    bfraw* c2raw = (bfraw*)(ws + alloc((size_t)64 * S4096 * 2));
    bfraw* cmb   = (bfraw*)(ws + alloc((size_t)64 * S4096 * 2));
    bfraw* msp   = (bfraw*)(ws + alloc((size_t)64 * S4096 * 2));
    float* vc    = (float*)(ws + alloc(3072 * 4));
    float* mch   = (float*)(ws + alloc(3072 * 4));
    float* weff  = (float*)(ws + alloc(256));
    bfraw* wF    = (bfraw*)(ws + alloc((size_t)55296 * 16));
    const size_t big_xF  = (size_t)S4096 * C384 * 2;   // per-batch xF bf16
    const size_t big_pre = (size_t)OC * S4096 * 2;     // per-batch qkv bf16
    const size_t big_av  = (size_t)768 * S4096 * 2;    // per-batch attn+v bf16
    int nb = (ws_size >= off + 8 * (big_xF + big_pre + big_av)) ? 8 : 1;
    bfraw* xF  = (bfraw*)(ws + alloc((size_t)nb * big_xF));
    bfraw* pre = (bfraw*)(ws + alloc((size_t)nb * big_pre));
    bfraw* av  = (bfraw*)(ws + alloc((size_t)nb * big_av));

    kA_prep<<<217, 256, 0, stream>>>(w_qkv, wF, w_attn_l, w_v_l, weff);
    for (int b0 = 0; b0 < 8; b0 += nb) {
        kB_tr<<<dim3(24, 16, nb), 256, 0, stream>>>(x, xF, b0);
        k1_gemm<<<dim3(8, 9, nb), 256, 0, stream>>>(wF, xF, pre, b0);
        k2f<<<dim3(384, nb), 256, 0, stream>>>(pre, w_dw, temp, av, b0);
        k4a<<<dim3(8, nb, 4), 256, 0, stream>>>(av, w_attn_r, weff, cmraw, c2raw, b0);
        k4b<<<dim3(8, nb), 256, 0, stream>>>(cmraw, c2raw, cmb, msp, b0);
        k5_vc<<<dim3(384, nb), 256, 0, stream>>>(av, cmb, vc, b0);
        k6_gate<<<dim3(nb), 256, 0, stream>>>(vc, w_v_r, w_up1, b_up1,
                                              ln_w, ln_b, w_up2, b_up2, mch, b0);
        k7_out<<<dim3(16, 8, nb), 256, 0, stream>>>(x, w_proj, mch, msp, out, b0);
    }
}

// Round 8
// 125.724 us; speedup vs baseline: 1.0886x; 1.0886x over previous
//
#include <hip/hip_runtime.h>
#include <math.h>

// ---------------------------------------------------------------------------
// DCMHSA fused pipeline, MI355X (gfx950)
// B=8, DIM=384, H=W=64 (S=4096), HEADS=8, D=48, D2=24, DU=32, OC=3*DIM=1152
// R8: k1 reverted to 1-tile/block; A-operand bypasses LDS (direct L2-resident
//     global_load_dwordx4 into registers, 1-iter pipelined). B via gll16
//     double-buffer. Halves LDS traffic. Rest as R7 (bf16 intermediates).
// ---------------------------------------------------------------------------

#define S4096 4096
#define C384  384
#define OC    1152

typedef unsigned short bfraw;   // bf16 bit pattern
typedef unsigned int   u32;
typedef __attribute__((ext_vector_type(8))) short bf16x8;   // 8 bf16 (4 VGPRs)
typedef __attribute__((ext_vector_type(4))) float f32x4;    // MFMA accumulator

typedef __attribute__((address_space(3))) unsigned int lds_u32;
typedef const __attribute__((address_space(1))) unsigned int glb_u32;
__device__ __forceinline__ void gll16(const void* g, void* l) {
    __builtin_amdgcn_global_load_lds((glb_u32*)g, (lds_u32*)l, 16, 0, 0);
}

__device__ __forceinline__ bfraw f2bf(float f) {
    union { float f; u32 u; } c; c.f = f;
    u32 r = c.u + 0x7FFFu + ((c.u >> 16) & 1u);   // RNE
    return (bfraw)(r >> 16);
}
__device__ __forceinline__ float bf2f(bfraw u) {
    union { u32 u; float f; } c; c.u = ((u32)u) << 16;
    return c.f;
}
__device__ __forceinline__ void unpack8(uint4 v, float* f) {
    f[0] = bf2f((bfraw)(v.x & 0xffff)); f[1] = bf2f((bfraw)(v.x >> 16));
    f[2] = bf2f((bfraw)(v.y & 0xffff)); f[3] = bf2f((bfraw)(v.y >> 16));
    f[4] = bf2f((bfraw)(v.z & 0xffff)); f[5] = bf2f((bfraw)(v.z >> 16));
    f[6] = bf2f((bfraw)(v.w & 0xffff)); f[7] = bf2f((bfraw)(v.w >> 16));
}
__device__ __forceinline__ uint4 pack8(const float* f) {
    union { bfraw us[8]; uint4 q; } p;
    #pragma unroll
    for (int i = 0; i < 8; i++) p.us[i] = f2bf(f[i]);
    return p.q;
}

// block=256 (4 waves) reduction; s4 is 4-float shared scratch
__device__ __forceinline__ float blk_red(float v, float* s4, bool ismax) {
    #pragma unroll
    for (int off = 32; off; off >>= 1) {
        float o = __shfl_down(v, off, 64);
        v = ismax ? fmaxf(v, o) : (v + o);
    }
    __syncthreads();                       // protect prior contents of s4
    if ((threadIdx.x & 63) == 0) s4[threadIdx.x >> 6] = v;
    __syncthreads();
    return ismax ? fmaxf(fmaxf(s4[0], s4[1]), fmaxf(s4[2], s4[3]))
                 : ((s4[0] + s4[1]) + (s4[2] + s4[3]));
}

// ---------------------------------------------------------------------------
// kA: blocks 0..215: w_qkv [1152][384] f32 -> wF fragment layout bf16.
//     block 216: data-independent weff prep.
// ---------------------------------------------------------------------------
__global__ __launch_bounds__(256) void kA_prep(
    const float* __restrict__ w_qkv, bfraw* __restrict__ wF,
    const float* __restrict__ w_attn_l, const float* __restrict__ w_v_l,
    float* __restrict__ weff) {
    if (blockIdx.x == 216) {
        __shared__ float avg[24];
        const int tid = threadIdx.x;
        if (tid < 24) {
            float a = 0.f;
            for (int d = 0; d < 48; d++) a += w_attn_l[tid * 48 + d];
            avg[tid] = a * (1.f / 4096.f);
        }
        __syncthreads();
        if (tid == 0) {
            float M = -3.402823466e+38f;
            for (int o = 0; o < 24; o++) M = fmaxf(M, avg[o]);
            float S = 0.f;
            for (int o = 0; o < 24; o++) { avg[o] = __expf(avg[o] - M); S += avg[o]; }
            float inv = 1.f / S;
            for (int o = 0; o < 24; o++) avg[o] *= inv;
        }
        __syncthreads();
        if (tid < 48) {
            float a = 0.f;
            for (int o = 0; o < 24; o++) a += avg[o] * w_v_l[o * 48 + tid];
            weff[tid] = a;
        }
        return;
    }
    const int id = blockIdx.x * 256 + threadIdx.x;   // < 55296
    const int ob = id / 768, rem = id % 768;
    const int c = rem / 48, kb = rem % 48;
    const float* src = w_qkv + (size_t)(ob * 16 + c) * C384 + kb * 8;
    float f[8];
    *(float4*)f       = *(const float4*)src;
    *(float4*)(f + 4) = *(const float4*)(src + 4);
    *(uint4*)&wF[((size_t)(ob * 48 + kb) * 16 + c) * 8] = pack8(f);
}

// ---------------------------------------------------------------------------
// kB: transpose+convert x[b][c][s] f32 -> xF[b][s/16][k/8][16][8] bf16.
// ---------------------------------------------------------------------------
__global__ __launch_bounds__(256) void kB_tr(
    const float* __restrict__ x, bfraw* __restrict__ xF, int b0) {
    const int cb = blockIdx.x, sb = blockIdx.y, bl = blockIdx.z;
    const int c0 = cb * 16, s0 = sb * 256;
    const int tid = threadIdx.x;
    __shared__ alignas(16) bfraw lt[16][264];   // pad 8 u16 (16 B)
    {
        const int r = tid >> 4, seg = tid & 15;
        const float* src = x + ((size_t)(b0 + bl) * C384 + c0 + r) * S4096 + s0 + seg * 16;
        float f[16];
        #pragma unroll
        for (int i = 0; i < 4; i++) *(float4*)(f + i * 4) = *(const float4*)(src + i * 4);
        *(uint4*)&lt[r][seg * 16]     = pack8(f);
        *(uint4*)&lt[r][seg * 16 + 8] = pack8(f + 8);
    }
    __syncthreads();
    const int sbl = tid >> 4, c = tid & 15;
    bfraw* xFb = xF + (size_t)bl * S4096 * C384;
    #pragma unroll
    for (int kbl = 0; kbl < 2; kbl++) {
        union { bfraw us[8]; uint4 q; } p;
        #pragma unroll
        for (int j = 0; j < 8; j++) p.us[j] = lt[kbl * 8 + j][sbl * 16 + c];
        const size_t idx = (((size_t)((s0 >> 4) + sbl) * 48) + (c0 >> 3) + kbl) * 128 + c * 8;
        *(uint4*)&xFb[idx] = p.q;
    }
}

// ---------------------------------------------------------------------------
// k1: pre[b,o,s] = sum_c w[o,c] x[b,c,s]  -- 128x128 tile, BK=32, 4 waves.
// A: direct global->register (wF is L2-resident, per-wave 1KB contiguous),
//    1-iteration register pipeline.  B: gll16 double-buffered LDS.
// grid (32 s-tiles, 9 o-tiles, nb)
// ---------------------------------------------------------------------------
__global__ __launch_bounds__(256) void k1_gemm(
    const bfraw* __restrict__ wF, const bfraw* __restrict__ xF,
    bfraw* __restrict__ pre, int b0) {
    __shared__ alignas(16) bfraw b_sm[2][4096];   // 2 x 8 KB B buffers
    const int tid = threadIdx.x;
    const int wave = tid >> 6, lane = tid & 63;
    const int sT = blockIdx.x, oT = blockIdx.y, bl = blockIdx.z;
    const bfraw* xFb = xF + (size_t)bl * S4096 * C384;

    const int c0_ = tid, c1_ = tid + 256;
    const int rb0 = c0_ >> 6, oc0 = (c0_ >> 4) & 3, rw0 = c0_ & 15;
    const int rb1 = c1_ >> 6, oc1 = (c1_ >> 4) & 3, rw1 = c1_ & 15;
    const bfraw* pB0 = xFb + ((size_t)((sT * 8 + rb0) * 48 + oc0) * 16 + rw0) * 8;
    const bfraw* pB1 = xFb + ((size_t)((sT * 8 + rb1) * 48 + oc1) * 16 + rw1) * 8;

    const int wr = (wave >> 1) * 4;   // A frag base (16-row units)
    const int wc = (wave & 1) * 4;    // B frag base (16-col units)
    const int l15 = lane & 15, kq = lane >> 4;

    // A-direct per-lane pointers (ks=0); K-step advance = 512 bfraw
    const bfraw* pA[4];
    #pragma unroll
    for (int m = 0; m < 4; m++)
        pA[m] = wF + (((size_t)(oT * 8 + wr + m) * 48 + kq) * 16 + l15) * 8;

    f32x4 acc[4][4];
    #pragma unroll
    for (int m = 0; m < 4; m++)
        #pragma unroll
        for (int n = 0; n < 4; n++) acc[m][n] = (f32x4){0, 0, 0, 0};

    // prologue: stage B(0), load A(0)
    gll16(pB0, &b_sm[0][(size_t)c0_ * 8]);
    gll16(pB1, &b_sm[0][(size_t)c1_ * 8]);
    bf16x8 a_cur[4];
    #pragma unroll
    for (int m = 0; m < 4; m++) a_cur[m] = *(const bf16x8*)(pA[m]);
    __syncthreads();

    #pragma unroll
    for (int ks = 0; ks < 12; ks++) {
        const bfraw* cb = b_sm[ks & 1];
        bf16x8 bq[4];
        #pragma unroll
        for (int n = 0; n < 4; n++)
            bq[n] = *(const bf16x8*)&cb[((wc + n) * 64 + lane) * 8];
        bf16x8 a_nxt[4];
        if (ks < 11) {
            bfraw* nb = (bfraw*)b_sm[(ks & 1) ^ 1];
            gll16(pB0 + (ks + 1) * 512, nb + (size_t)c0_ * 8);
            gll16(pB1 + (ks + 1) * 512, nb + (size_t)c1_ * 8);
            #pragma unroll
            for (int m = 0; m < 4; m++)
                a_nxt[m] = *(const bf16x8*)(pA[m] + (ks + 1) * 512);
        }
        __builtin_amdgcn_s_setprio(1);
        #pragma unroll
        for (int m = 0; m < 4; m++)
            #pragma unroll
            for (int n = 0; n < 4; n++)
                acc[m][n] = __builtin_amdgcn_mfma_f32_16x16x32_bf16(a_cur[m], bq[n], acc[m][n], 0, 0, 0);
        __builtin_amdgcn_s_setprio(0);
        if (ks < 11) {
            #pragma unroll
            for (int m = 0; m < 4; m++) a_cur[m] = a_nxt[m];
        }
        __syncthreads();
    }

    // epilogue: direct stores (C/D layout col=lane&15, row=(lane>>4)*4+r)
    bfraw* op = pre + (size_t)bl * OC * S4096;
    const int orow0 = oT * 128 + (wave >> 1) * 64 + (lane >> 4) * 4;
    const int scol0 = sT * 128 + (wave & 1) * 64 + l15;
    #pragma unroll
    for (int m = 0; m < 4; m++)
        #pragma unroll
        for (int n = 0; n < 4; n++)
            #pragma unroll
            for (int r = 0; r < 4; r++)
                op[(size_t)(orow0 + m * 16 + r) * S4096 + scol0 + n * 16] = f2bf(acc[m][n][r]);
}

// ---------------------------------------------------------------------------
// k2f: fused depthwise 3x3 + norms + softmax stats + attn write.
// ---------------------------------------------------------------------------
__device__ __forceinline__ void stencil8(const bfraw* plane, const float* w9,
                                         int ypad, int k7, int x0, float* acc) {
    #pragma unroll
    for (int j = 0; j < 8; j++) acc[j] = 0.f;
    #pragma unroll
    for (int dy = 0; dy < 3; dy++) {
        uint4 rv = *(const uint4*)&plane[(ypad + dy) * 64 + x0];
        float r[8]; unpack8(rv, r);
        float lft = __shfl_up(r[7], 1);
        float rgt = __shfl_down(r[0], 1);
        if (k7 == 0) lft = 0.f;
        if (k7 == 7) rgt = 0.f;
        const float w0 = w9[dy*3], w1 = w9[dy*3+1], w2 = w9[dy*3+2];
        acc[0] += w0*lft + w1*r[0] + w2*r[1];
        #pragma unroll
        for (int j = 1; j < 7; j++) acc[j] += w0*r[j-1] + w1*r[j] + w2*r[j+1];
        acc[7] += w0*r[6] + w1*r[7] + w2*rgt;
    }
}

__global__ __launch_bounds__(256) void k2f(
    const bfraw* __restrict__ pre, const float* __restrict__ w_dw,
    const float* __restrict__ temperature,
    bfraw* __restrict__ av, int b0) {
    const int idx = blockIdx.x;            // h*48+d
    const int bl  = blockIdx.y;
    const int h   = idx / 48;
    const int tid = threadIdx.x;
    __shared__ alignas(16) bfraw pl[3][66 * 64];   // rows -1..64 zero-padded
    __shared__ float s4[4];

    const size_t pbase = (size_t)bl * OC * S4096;
    #pragma unroll
    for (int p = 0; p < 3; p++) {
        const bfraw* src = pre + pbase + (size_t)(idx + p * C384) * S4096;
        uint4 a = *(const uint4*)&src[tid * 16];
        uint4 b = *(const uint4*)&src[tid * 16 + 8];
        int y = tid >> 2, xq = (tid & 3) * 16;
        *(uint4*)&pl[p][(y + 1) * 64 + xq]     = a;
        *(uint4*)&pl[p][(y + 1) * 64 + xq + 8] = b;
    }
    if (tid < 64) {
        #pragma unroll
        for (int p = 0; p < 3; p++) { pl[p][tid] = 0; pl[p][65 * 64 + tid] = 0; }
    }
    float wq[9], wk[9], wv[9];
    #pragma unroll
    for (int i = 0; i < 9; i++) {
        wq[i] = w_dw[idx * 9 + i];
        wk[i] = w_dw[(idx + C384) * 9 + i];
        wv[i] = w_dw[(idx + 768) * 9 + i];
    }
    __syncthreads();

    const int sid0 = tid,        y0 = sid0 >> 3, k70 = sid0 & 7, x00 = k70 * 8;
    const int sid1 = tid + 256,  y1 = sid1 >> 3, k71 = sid1 & 7, x01 = k71 * 8;
    float qo[16], ko[16], vo[16];
    stencil8(pl[0], wq, y0, k70, x00, qo);
    stencil8(pl[0], wq, y1, k71, x01, qo + 8);
    stencil8(pl[1], wk, y0, k70, x00, ko);
    stencil8(pl[1], wk, y1, k71, x01, ko + 8);
    stencil8(pl[2], wv, y0, k70, x00, vo);
    stencil8(pl[2], wv, y1, k71, x01, vo + 8);

    float sq = 0.f, sk = 0.f;
    #pragma unroll
    for (int i = 0; i < 16; i++) { sq += qo[i] * qo[i]; sk += ko[i] * ko[i]; }
    float Sq = blk_red(sq, s4, false);
    float Sk = blk_red(sk, s4, false);
    float scale = temperature[h] /
        (fmaxf(sqrtf(Sq), 1e-12f) * fmaxf(sqrtf(Sk), 1e-12f));
    float lm = -3.402823466e+38f;
    #pragma unroll
    for (int i = 0; i < 16; i++) { qo[i] = qo[i] * ko[i] * scale; lm = fmaxf(lm, qo[i]); }
    float M = blk_red(lm, s4, true);
    float ls = 0.f;
    #pragma unroll
    for (int i = 0; i < 16; i++) { qo[i] = __expf(qo[i] - M); ls += qo[i]; }
    float Z = blk_red(ls, s4, false);
    float invZ = 1.f / Z;
    #pragma unroll
    for (int i = 0; i < 16; i++) qo[i] *= invZ;

    bfraw* adst = av + ((size_t)bl * 768 + idx) * S4096;
    bfraw* vdst = av + ((size_t)bl * 768 + 384 + idx) * S4096;
    *(uint4*)&adst[y0 * 64 + x00] = pack8(qo);
    *(uint4*)&adst[y1 * 64 + x01] = pack8(qo + 8);
    *(uint4*)&vdst[y0 * 64 + x00] = pack8(vo);
    *(uint4*)&vdst[y1 * 64 + x01] = pack8(vo + 8);
}

// ---------------------------------------------------------------------------
// k4a: partial sums over d, s-tiled.  grid (8, nb, 4).  bf16 outputs.
// ---------------------------------------------------------------------------
__global__ __launch_bounds__(256) void k4a(
    const bfraw* __restrict__ av, const float* __restrict__ w_attn_r,
    const float* __restrict__ weff,
    bfraw* __restrict__ cmraw, bfraw* __restrict__ c2raw, int b0) {
    const int h = blockIdx.x, bl = blockIdx.y, st = blockIdx.z;
    const int b = b0 + bl;
    const int tid = threadIdx.x;
    __shared__ float swr[48], swf[48];
    if (tid < 48) { swr[tid] = w_attn_r[tid]; swf[tid] = weff[tid]; }
    __syncthreads();
    const int s_off = st * 1024 + tid * 4;
    const bfraw* abase = av + ((size_t)bl * 768 + h * 48) * S4096 + s_off;
    const bfraw* vbase = abase + (size_t)384 * S4096;
    float cmr[4] = {0,0,0,0}, c2[4] = {0,0,0,0};
    for (int d = 0; d < 48; d++) {
        uint2 ua = *(const uint2*)(abase + (size_t)d * S4096);
        uint2 uv = *(const uint2*)(vbase + (size_t)d * S4096);
        const float wr = swr[d], wf = swf[d];
        cmr[0] += bf2f((bfraw)(ua.x & 0xffff)) * wr;
        cmr[1] += bf2f((bfraw)(ua.x >> 16))    * wr;
        cmr[2] += bf2f((bfraw)(ua.y & 0xffff)) * wr;
        cmr[3] += bf2f((bfraw)(ua.y >> 16))    * wr;
        c2[0]  += bf2f((bfraw)(uv.x & 0xffff)) * wf;
        c2[1]  += bf2f((bfraw)(uv.x >> 16))    * wf;
        c2[2]  += bf2f((bfraw)(uv.y & 0xffff)) * wf;
        c2[3]  += bf2f((bfraw)(uv.y >> 16))    * wf;
    }
    const size_t o = ((size_t)(b * 8 + h)) * S4096 + s_off;
    union { bfraw us[4]; uint2 q; } pa, pb;
    #pragma unroll
    for (int j = 0; j < 4; j++) { pa.us[j] = f2bf(cmr[j]); pb.us[j] = f2bf(c2[j]); }
    *(uint2*)(cmraw + o) = pa.q;
    *(uint2*)(c2raw + o) = pb.q;
}

// ---------------------------------------------------------------------------
// k4b: softmax_s(cmraw) -> cmb (bf16);  sigmoid(c2raw) -> msp (bf16).
// ---------------------------------------------------------------------------
__global__ __launch_bounds__(256) void k4b(
    const bfraw* __restrict__ cmraw, const bfraw* __restrict__ c2raw,
    bfraw* __restrict__ cmb, bfraw* __restrict__ msp, int b0) {
    const int h = blockIdx.x, bl = blockIdx.y, b = b0 + bl;
    const int tid = threadIdx.x;
    __shared__ float s4[4];
    const size_t base = ((size_t)(b * 8 + h)) * S4096 + tid * 16;
    float v[16];
    { uint4 a = *(const uint4*)(cmraw + base), c = *(const uint4*)(cmraw + base + 8);
      unpack8(a, v); unpack8(c, v + 8); }
    float lm = -3.402823466e+38f;
    #pragma unroll
    for (int i = 0; i < 16; i++) lm = fmaxf(lm, v[i]);
    float M = blk_red(lm, s4, true);
    float ls = 0.f;
    #pragma unroll
    for (int i = 0; i < 16; i++) { v[i] = __expf(v[i] - M); ls += v[i]; }
    float Z = blk_red(ls, s4, false);
    float inv = 1.f / Z;
    #pragma unroll
    for (int i = 0; i < 16; i++) v[i] *= inv;
    *(uint4*)(cmb + base)     = pack8(v);
    *(uint4*)(cmb + base + 8) = pack8(v + 8);
    float sg[16];
    { uint4 a = *(const uint4*)(c2raw + base), c = *(const uint4*)(c2raw + base + 8);
      unpack8(a, sg); unpack8(c, sg + 8); }
    #pragma unroll
    for (int i = 0; i < 16; i++) sg[i] = 1.f / (1.f + __expf(-sg[i]));
    *(uint4*)(msp + base)     = pack8(sg);
    *(uint4*)(msp + base + 8) = pack8(sg + 8);
}

// ---------------------------------------------------------------------------
// k5: vc[b,h,d] = sum_s cmb[b,h,s]*v[b,h,d,s].   grid (384, nb)
// ---------------------------------------------------------------------------
__global__ __launch_bounds__(256) void k5_vc(
    const bfraw* __restrict__ av, const bfraw* __restrict__ cmb,
    float* __restrict__ vc, int b0) {
    const int idx = blockIdx.x;            // h*48+d
    const int bl = blockIdx.y, b = b0 + bl;
    const int h = idx / 48;
    const int tid = threadIdx.x;
    const bfraw* vr = av + ((size_t)bl * 768 + 384 + idx) * S4096 + tid * 16;
    const bfraw* cr = cmb + ((size_t)(b * 8 + h)) * S4096 + tid * 16;
    float vv[16], cc[16];
    { uint4 a = *(const uint4*)vr, c = *(const uint4*)(vr + 8); unpack8(a, vv); unpack8(c, vv + 8); }
    { uint4 a = *(const uint4*)cr, c = *(const uint4*)(cr + 8); unpack8(a, cc); unpack8(c, cc + 8); }
    float a = 0.f;
    #pragma unroll
    for (int i = 0; i < 16; i++) a += vv[i] * cc[i];
    __shared__ float s4[4];
    float S = blk_red(a, s4, false);
    if (tid == 0) vc[b * C384 + idx] = S;
}

// ---------------------------------------------------------------------------
// k6: channel gate: ctx -> up1 -> LayerNorm(32x8) -> relu -> up2 -> sigmoid.
// ---------------------------------------------------------------------------
__global__ __launch_bounds__(256) void k6_gate(
    const float* __restrict__ vc, const float* __restrict__ w_v_r,
    const float* __restrict__ w_up1, const float* __restrict__ b_up1,
    const float* __restrict__ ln_w, const float* __restrict__ ln_b,
    const float* __restrict__ w_up2, const float* __restrict__ b_up2,
    float* __restrict__ mch, int b0) {
    const int b = b0 + blockIdx.x;
    const int tid = threadIdx.x;
    __shared__ float s_vc[384], s_ctx[192], s_u[256], s4[4];
    for (int i = tid; i < 384; i += 256) s_vc[i] = vc[b * C384 + i];
    __syncthreads();
    if (tid < 192) {
        int hh = tid / 24, o = tid % 24;
        float a = 0.f;
        for (int d = 0; d < 48; d++) a += w_v_r[o * 48 + d] * s_vc[hh * 48 + d];
        s_ctx[hh * 24 + o] = a;
    }
    __syncthreads();
    float uval;
    {
        int o = tid >> 3, hh = tid & 7;
        float a = b_up1[o];
        for (int c = 0; c < 24; c++) a += w_up1[o * 24 + c] * s_ctx[hh * 24 + c];
        uval = a;
    }
    float mu  = blk_red(uval, s4, false) * (1.f / 256.f);
    float dv  = uval - mu;
    float var = blk_red(dv * dv, s4, false) * (1.f / 256.f);
    float un  = dv * rsqrtf(var + 1e-5f) * ln_w[tid] + ln_b[tid];
    s_u[tid] = fmaxf(un, 0.f);
    __syncthreads();
    for (int t = tid; t < 384; t += 256) {
        int o2 = t >> 3, hh = t & 7;
        float a = b_up2[o2];
        for (int o = 0; o < 32; o++) a += w_up2[o2 * 32 + o] * s_u[o * 8 + hh];
        mch[b * C384 + t] = 1.f / (1.f + __expf(-a));
    }
}

// ---------------------------------------------------------------------------
// k7: out[b,c,s] = x[b,c,s] * ( mask_ch[b,c] + sum_h w_proj[c,h]*msp[b,h,s] )
// grid (16 s-tiles of 256, 8 c-groups of 48, nb).  msp (bf16) -> LDS f32.
// ---------------------------------------------------------------------------
__global__ __launch_bounds__(256) void k7_out(
    const float* __restrict__ x, const float* __restrict__ w_proj,
    const float* __restrict__ mch, const bfraw* __restrict__ msp,
    float* __restrict__ out, int b0) {
    const int st = blockIdx.x, cg = blockIdx.y, bl = blockIdx.z;
    const int b = b0 + bl;
    const int tid = threadIdx.x;
    const int s0 = st * 256, c0 = cg * 48;
    __shared__ float s_msp[8][256];
    __shared__ float s_mch[48];
    __shared__ float s_wp[48][8];
    for (int i = tid; i < 2048; i += 256) {
        int hh = i >> 8, ss = i & 255;
        s_msp[hh][ss] = bf2f(msp[((size_t)(b * 8 + hh)) * S4096 + s0 + ss]);
    }
    if (tid < 48) s_mch[tid] = mch[b * C384 + c0 + tid];
    for (int i = tid; i < 384; i += 256)
        s_wp[i >> 3][i & 7] = w_proj[(size_t)(c0 + (i >> 3)) * 8 + (i & 7)];
    __syncthreads();

    const int cl = tid >> 6;           // 0..3 (wave-uniform)
    const int s4i = (tid & 63) * 4;    // float4 slot in s-tile
    float4 m[8];
    #pragma unroll
    for (int hh = 0; hh < 8; hh++) m[hh] = *(const float4*)&s_msp[hh][s4i];

    #pragma unroll 4
    for (int j = 0; j < 12; j++) {
        const int cloc = j * 4 + cl;
        const int c = c0 + cloc;
        const float base = s_mch[cloc];
        float4 a = {base, base, base, base};
        #pragma unroll
        for (int hh = 0; hh < 8; hh++) {
            const float wp = s_wp[cloc][hh];
            a.x += wp * m[hh].x; a.y += wp * m[hh].y;
            a.z += wp * m[hh].z; a.w += wp * m[hh].w;
        }
        const size_t o = ((size_t)b * C384 + c) * S4096 + s0 + s4i;
        float4 xv = *(const float4*)(x + o);
        a.x *= xv.x; a.y *= xv.y; a.z *= xv.z; a.w *= xv.w;
        *(float4*)(out + o) = a;
    }
}

// ---------------------------------------------------------------------------
extern "C" void kernel_launch(void* const* d_in, const int* in_sizes, int n_in,
                              void* d_out, int out_size, void* d_ws, size_t ws_size,
                              hipStream_t stream) {
    const float* x        = (const float*)d_in[0];
    const float* temp     = (const float*)d_in[1];
    const float* w_qkv    = (const float*)d_in[2];
    const float* w_dw     = (const float*)d_in[3];
    const float* w_proj   = (const float*)d_in[4];
    const float* w_attn_r = (const float*)d_in[5];
    const float* w_v_r    = (const float*)d_in[6];
    const float* w_up1    = (const float*)d_in[7];
    const float* b_up1    = (const float*)d_in[8];
    const float* ln_w     = (const float*)d_in[9];
    const float* ln_b     = (const float*)d_in[10];
    const float* w_up2    = (const float*)d_in[11];
    const float* b_up2    = (const float*)d_in[12];
    const float* w_attn_l = (const float*)d_in[13];
    const float* w_v_l    = (const float*)d_in[14];
    float* out = (float*)d_out;
    char* ws = (char*)d_ws;

    size_t off = 0;
    auto alloc = [&](size_t bytes) {
        size_t o = off; off = (off + bytes + 255) & ~(size_t)255; return o;
    };
    bfraw* cmraw = (bfraw*)(ws + alloc((size_t)64 * S4096 * 2));
    bfraw* c2raw = (bfraw*)(ws + alloc((size_t)64 * S4096 * 2));
    bfraw* cmb   = (bfraw*)(ws + alloc((size_t)64 * S4096 * 2));
    bfraw* msp   = (bfraw*)(ws + alloc((size_t)64 * S4096 * 2));
    float* vc    = (float*)(ws + alloc(3072 * 4));
    float* mch   = (float*)(ws + alloc(3072 * 4));
    float* weff  = (float*)(ws + alloc(256));
    bfraw* wF    = (bfraw*)(ws + alloc((size_t)55296 * 16));
    const size_t big_xF  = (size_t)S4096 * C384 * 2;   // per-batch xF bf16
    const size_t big_pre = (size_t)OC * S4096 * 2;     // per-batch qkv bf16
    const size_t big_av  = (size_t)768 * S4096 * 2;    // per-batch attn+v bf16
    int nb = (ws_size >= off + 8 * (big_xF + big_pre + big_av)) ? 8 : 1;
    bfraw* xF  = (bfraw*)(ws + alloc((size_t)nb * big_xF));
    bfraw* pre = (bfraw*)(ws + alloc((size_t)nb * big_pre));
    bfraw* av  = (bfraw*)(ws + alloc((size_t)nb * big_av));

    kA_prep<<<217, 256, 0, stream>>>(w_qkv, wF, w_attn_l, w_v_l, weff);
    for (int b0 = 0; b0 < 8; b0 += nb) {
        kB_tr<<<dim3(24, 16, nb), 256, 0, stream>>>(x, xF, b0);
        k1_gemm<<<dim3(32, 9, nb), 256, 0, stream>>>(wF, xF, pre, b0);
        k2f<<<dim3(384, nb), 256, 0, stream>>>(pre, w_dw, temp, av, b0);
        k4a<<<dim3(8, nb, 4), 256, 0, stream>>>(av, w_attn_r, weff, cmraw, c2raw, b0);
        k4b<<<dim3(8, nb), 256, 0, stream>>>(cmraw, c2raw, cmb, msp, b0);
        k5_vc<<<dim3(384, nb), 256, 0, stream>>>(av, cmb, vc, b0);
        k6_gate<<<dim3(nb), 256, 0, stream>>>(vc, w_v_r, w_up1, b_up1,
                                              ln_w, ln_b, w_up2, b_up2, mch, b0);
        k7_out<<<dim3(16, 8, nb), 256, 0, stream>>>(x, w_proj, mch, msp, out, b0);
    }
}